// Round 11
// baseline (403.445 us; speedup 1.0000x reference)
//
#include <hip/hip_runtime.h>

// Problem constants (from setup_inputs): z (8,256,32,32), weight (16384,256)
#define NB   8
#define DIM  256
#define HW   1024          // 32*32
#define NZ   8192          // NB*HW flattened z rows
#define KC   16384         // codebook entries
#define DECAYF 0.99f
#define ONEMDECAY 0.01f
#define EPSF 1e-5f
#define BETAF 0.25f
// logical K = 768 ([ah|al|ah].[bh|bh|bl]); physical layout is dedup'd:
// Acat = [ah|al] (512), Bcat = [bh|bl] (512); segment->phys remap in STAGE.
#define APHYS 512

typedef _Float16 half8 __attribute__((ext_vector_type(8)));
typedef _Float16 half4 __attribute__((ext_vector_type(4)));
typedef float floatx4 __attribute__((ext_vector_type(4)));

// Output offsets (floats) in d_out, in reference return order
#define O_ZQ   0u
#define O_LOSS 2097152u
#define O_PERP 2097153u
#define O_IDX  2097154u
#define O_NW   2105346u
#define O_NCS  6299650u
#define O_NEA  6316034u

// ws layout (floats)
#define W_ZT     0u          // 8192*256 fp32
#define W_WSQ    2097152u    // 16384
#define W_CNT    2113536u    // 16384           (zeroed)
#define W_SCAL   2129920u    // 4: [0]=loss [1]=n_sum [2]=plogp (zeroed)
#define W_PACKED 2129924u    // 8192 u64 (byte off %8==0) (memset 0xFF)
#define W_ACAT   2146308u    // 8192*512 f16  (byte off %16==0)
#define W_BCAT   4243460u    // 16384*512 f16 (byte off %16==0)
#define WS_FLOATS_OLD 2146308u
#define WS_FLOATS_NEW 8437764u

// ---------------- K0 (fused): prep (wsq + Bcat + out6) AND transpose (zt + Acat)
// Independent streams fused into one launch: blocks [0, KC/4) do prep,
// blocks [KC/4, KC/4+512) do the z transpose.
template <bool SPLIT>
__global__ void k_prep_fused(const float* __restrict__ z, const float* __restrict__ w,
                             const float* __restrict__ ea, float* __restrict__ zt,
                             _Float16* __restrict__ Acat, float* __restrict__ wsq,
                             _Float16* __restrict__ Bcat, float* __restrict__ out6) {
  __shared__ float tile[64][65];
  if (blockIdx.x < KC / 4) {
    int wave = threadIdx.x >> 6, lane = threadIdx.x & 63;
    int k = blockIdx.x * 4 + wave;
    float4 v = *(const float4*)&w[(size_t)k * DIM + lane * 4];
    float s = v.x * v.x + v.y * v.y + v.z * v.z + v.w * v.w;
#pragma unroll
    for (int off = 32; off; off >>= 1) s += __shfl_xor(s, off);
    if (lane == 0) wsq[k] = s;
    if (SPLIT) {
      half4 h = { (_Float16)v.x, (_Float16)v.y, (_Float16)v.z, (_Float16)v.w };
      half4 lo = { (_Float16)(v.x - (float)h.x), (_Float16)(v.y - (float)h.y),
                   (_Float16)(v.z - (float)h.z), (_Float16)(v.w - (float)h.w) };
      size_t bbase = (size_t)k * APHYS + lane * 4;
      *(half4*)&Bcat[bbase] = h;          // phys seg0 = bh
      *(half4*)&Bcat[bbase + 256] = lo;   // phys seg1 = bl
    }
    float4 e = *(const float4*)&ea[(size_t)k * DIM + lane * 4];
    float4 o = { DECAYF * e.x, DECAYF * e.y, DECAYF * e.z, DECAYF * e.w };
    *(float4*)&out6[(size_t)k * DIM + lane * 4] = o;
  } else {
    int flat = blockIdx.x - KC / 4;
    int hwb = (flat & 15) * 64, db = ((flat >> 4) & 3) * 64, b = flat >> 6;
    int lane = threadIdx.x & 63, sub = threadIdx.x >> 6;
#pragma unroll
    for (int i = 0; i < 16; ++i) {
      int dof = sub * 16 + i;
      tile[dof][lane] = z[((size_t)(b * DIM + db + dof)) * HW + hwb + lane];
    }
    __syncthreads();
#pragma unroll
    for (int i = 0; i < 16; ++i) {
      int hwof = sub * 16 + i;
      int n = b * HW + hwb + hwof;
      float val = tile[lane][hwof];
      zt[(size_t)n * DIM + db + lane] = val;
      if (SPLIT) {
        _Float16 h = (_Float16)val;
        _Float16 lo = (_Float16)(val - (float)h);
        size_t abase = (size_t)n * APHYS + db + lane;
        Acat[abase] = h;          // phys seg0 = ah
        Acat[abase + 256] = lo;   // phys seg1 = al
      }
    }
  }
}

// ---------------- K5: transpose zt[n][d] (holds z_q_st) -> out0 (b,c,h,w) -------
__global__ void k_transpose_out(const float* __restrict__ zt, float* __restrict__ out0) {
  __shared__ float tile[64][65];
  int hwb = blockIdx.x * 64, db = blockIdx.y * 64, b = blockIdx.z;
  int lane = threadIdx.x & 63, sub = threadIdx.x >> 6;
#pragma unroll
  for (int i = 0; i < 16; ++i) {
    int hwof = sub * 16 + i;
    tile[hwof][lane] = zt[((size_t)(b * HW + hwb + hwof)) * DIM + db + lane];
  }
  __syncthreads();
#pragma unroll
  for (int i = 0; i < 16; ++i) {
    int dof = sub * 16 + i;
    out0[((size_t)(b * DIM + db + dof)) * HW + hwb + lane] = tile[lane][dof];
  }
}

// ---------------- K2: 128x256 MFMA distance GEMM + fused argmin ------------------
// 8 waves (2M x 4N), per-wave output 64x64 (acc 64 regs -> 4 waves/SIMD ->
// 2 blocks/CU, 48 KB single-buffered LDS; cross-block overlap hides staging).
// K-loop FULLY UNROLLED: all staging offsets are immediates (cuts the 31%
// VALUBusy address-recompute observed in R10).
#define GBM 128
#define GBN 256
#define GBK 64
#define NSTEP 12            // logical K = 768

__device__ __forceinline__ void gload16(const _Float16* g, _Float16* lds) {
  __builtin_amdgcn_global_load_lds((__attribute__((address_space(1))) void*)g,
                                   (__attribute__((address_space(3))) void*)lds, 16, 0, 0);
}

#define WAITVM0   asm volatile("s_waitcnt vmcnt(0)" ::: "memory")
#define WAITLGKM0 asm volatile("s_waitcnt lgkmcnt(0)" ::: "memory")
#define BAR       __builtin_amdgcn_s_barrier()

__global__ __launch_bounds__(512, 4) void k_argmin_mfma(const _Float16* __restrict__ Acat,
                                                        const _Float16* __restrict__ Bcat,
                                                        const float* __restrict__ wsq,
                                                        unsigned long long* __restrict__ packed) {
  __shared__ __align__(16) _Float16 As[GBM * GBK];   // 16 KB
  __shared__ __align__(16) _Float16 Bs[GBN * GBK];   // 32 KB  (total 48 KB)
  const int tid = threadIdx.x;
  const int w = tid >> 6, l = tid & 63;
  const int lr = l & 15, lc = l >> 4;
  const int wr = w >> 2, wc = w & 3;   // 2 x 4 wave grid, 64x64 per wave
  // XCD ownership: xcd = bid&7 owns 8 n-panels (L2-resident Bcat slice);
  // m-major order within the XCD reuses each A panel across its n-panels.
  const int bid = (int)blockIdx.x;
  const int xcd = bid & 7, local = bid >> 3;           // 4096 blocks total
  const int m0 = (local >> 3) * GBM;                   // 64 m-tiles
  const int n0 = (xcd * 8 + (local & 7)) * GBN;        // 64 n-tiles

  floatx4 acc[4][4];
#pragma unroll
  for (int i = 0; i < 4; ++i)
#pragma unroll
    for (int j = 0; j < 4; ++j) acc[i][j] = (floatx4){0.f, 0.f, 0.f, 0.f};

  // staging: LDS linear dest; global source pre-swizzled chunk^(row&7) so the
  // frag ds_read_b128 (row stride 128B) is bank-conflict-free.
  const int srow = (l >> 3);
  const int schk = (l & 7);

  // Loop-invariant base pointers (per-lane); per-step offsets are immediates.
  const _Float16* agbase[2];
  const _Float16* bgbase[4];
  _Float16* aldsbase[2];
  _Float16* bldsbase[4];
#pragma unroll
  for (int c = 0; c < 2; ++c) {
    int row = (w * 2 + c) * 8 + srow;
    int sc_ = schk ^ (row & 7);
    agbase[c] = Acat + (size_t)(m0 + row) * APHYS + sc_ * 8;
    aldsbase[c] = &As[(w * 2 + c) * 512];
  }
#pragma unroll
  for (int c = 0; c < 4; ++c) {
    int row = (w * 4 + c) * 8 + srow;
    int sc_ = schk ^ (row & 7);
    bgbase[c] = Bcat + (size_t)(n0 + row) * APHYS + sc_ * 8;
    bldsbase[c] = &Bs[(w * 4 + c) * 512];
  }

  // logical step -> physical offsets: seg = STEP>>2 (0:ah.bh 1:al.bh 2:ah.bl)
#define STAGE(STEP)                                                               \
  {                                                                               \
    const int aoff_ = (((STEP) >> 2) == 1 ? 256 : 0) + ((STEP) & 3) * 64;         \
    const int boff_ = (((STEP) >> 2) == 2 ? 256 : 0) + ((STEP) & 3) * 64;         \
    _Pragma("unroll")                                                             \
    for (int c = 0; c < 2; ++c) gload16(agbase[c] + aoff_, aldsbase[c]);          \
    _Pragma("unroll")                                                             \
    for (int c = 0; c < 4; ++c) gload16(bgbase[c] + boff_, bldsbase[c]);          \
  }

#pragma unroll
  for (int t = 0; t < NSTEP; ++t) {
    STAGE(t);
    WAITVM0;                 // my 6 stage-loads landed
    BAR;                     // everyone's landed -> tile valid
#pragma unroll
    for (int kk = 0; kk < 2; ++kk) {
      half8 af[4], bf[4];
#pragma unroll
      for (int mi = 0; mi < 4; ++mi) {
        int row = wr * 64 + mi * 16 + lr;
        int ch = (kk * 4 + lc) ^ (row & 7);
        af[mi] = *(const half8*)&As[row * GBK + ch * 8];
      }
#pragma unroll
      for (int ni = 0; ni < 4; ++ni) {
        int row = wc * 64 + ni * 16 + lr;
        int ch = (kk * 4 + lc) ^ (row & 7);
        bf[ni] = *(const half8*)&Bs[row * GBK + ch * 8];
      }
#pragma unroll
      for (int mi = 0; mi < 4; ++mi)
#pragma unroll
        for (int ni = 0; ni < 4; ++ni)
          acc[mi][ni] = __builtin_amdgcn_mfma_f32_16x16x32_f16(af[mi], bf[ni], acc[mi][ni], 0, 0, 0);
    }
    WAITLGKM0;               // my LDS reads retired
    BAR;                     // everyone done reading -> safe to overwrite
  }
#undef STAGE

  // epilogue: per-row argmin. C layout: col = lane&15, row = (lane>>4)*4 + reg.
  // best[] aliases the A buffer (final BAR above bounds all reads).
  unsigned long long* best = (unsigned long long*)&As[0];
  if (tid < GBM) best[tid] = ~0ull;
  __syncthreads();
  float sc4[4];
  int col4[4];
#pragma unroll
  for (int ni = 0; ni < 4; ++ni) {
    col4[ni] = n0 + wc * 64 + ni * 16 + lr;
    sc4[ni] = wsq[col4[ni]];
  }
#pragma unroll
  for (int mi = 0; mi < 4; ++mi) {
#pragma unroll
    for (int r = 0; r < 4; ++r) {
      unsigned long long bv = ~0ull;
#pragma unroll
      for (int ni = 0; ni < 4; ++ni) {
        float score = fmaf(-2.0f, acc[mi][ni][r], sc4[ni]);
        unsigned u = __float_as_uint(score);
        u ^= (unsigned)(((int)u >> 31) | 0x80000000);  // monotonic float->uint
        unsigned long long p = ((unsigned long long)u << 32) | (unsigned)col4[ni];
        bv = p < bv ? p : bv;
      }
#pragma unroll
      for (int off = 1; off < 16; off <<= 1) {
        unsigned long long o = __shfl_xor(bv, off);
        bv = o < bv ? o : bv;
      }
      if (lr == 0) atomicMin(&best[wr * 64 + mi * 16 + lc * 4 + r], bv);
    }
  }
  __syncthreads();
  if (tid < GBM) atomicMin(&packed[m0 + tid], best[tid]);
}

// ---------------- Fallback fp32 GEMM+argmin -------------------------------------
#define TM 128
#define TN 128
#define DK 32
#define PADL 33
__global__ __launch_bounds__(256) void k_argmin_fp32(const float* __restrict__ zt,
                                                     const float* __restrict__ w,
                                                     const float* __restrict__ wsq,
                                                     unsigned long long* __restrict__ packed) {
  __shared__ float As[TM * PADL];
  __shared__ float Ws[TN * PADL];
  __shared__ unsigned long long best[TM];
  const int tid = threadIdx.x;
  const int k0 = blockIdx.x * TN, m0 = blockIdx.y * TM;
  if (tid < TM) best[tid] = ~0ull;
  const int tx = tid & 15, ty = tid >> 4;
  const int mrow = tid & 127;
  const int q = (tid >> 7) * 16;

  float acc[8][8];
#pragma unroll
  for (int i = 0; i < 8; ++i)
#pragma unroll
    for (int j = 0; j < 8; ++j) acc[i][j] = 0.0f;

  for (int dbase = 0; dbase < DIM; dbase += DK) {
    __syncthreads();
    const float* za = &zt[(size_t)(m0 + mrow) * DIM + dbase + q];
    const float* wa = &w[(size_t)(k0 + mrow) * DIM + dbase + q];
    float4 a0 = *(const float4*)(za + 0), a1 = *(const float4*)(za + 4);
    float4 a2 = *(const float4*)(za + 8), a3 = *(const float4*)(za + 12);
    float4 b0 = *(const float4*)(wa + 0), b1 = *(const float4*)(wa + 4);
    float4 b2 = *(const float4*)(wa + 8), b3 = *(const float4*)(wa + 12);
    float* Ap = &As[mrow * PADL + q];
    float* Wp = &Ws[mrow * PADL + q];
    Ap[0] = a0.x; Ap[1] = a0.y; Ap[2] = a0.z; Ap[3] = a0.w;
    Ap[4] = a1.x; Ap[5] = a1.y; Ap[6] = a1.z; Ap[7] = a1.w;
    Ap[8] = a2.x; Ap[9] = a2.y; Ap[10] = a2.z; Ap[11] = a2.w;
    Ap[12] = a3.x; Ap[13] = a3.y; Ap[14] = a3.z; Ap[15] = a3.w;
    Wp[0] = b0.x; Wp[1] = b0.y; Wp[2] = b0.z; Wp[3] = b0.w;
    Wp[4] = b1.x; Wp[5] = b1.y; Wp[6] = b1.z; Wp[7] = b1.w;
    Wp[8] = b2.x; Wp[9] = b2.y; Wp[10] = b2.z; Wp[11] = b2.w;
    Wp[12] = b3.x; Wp[13] = b3.y; Wp[14] = b3.z; Wp[15] = b3.w;
    __syncthreads();
#pragma unroll
    for (int d = 0; d < DK; ++d) {
      float a[8], b[8];
#pragma unroll
      for (int i = 0; i < 4; ++i) {
        a[i]     = As[(ty * 4 + i) * PADL + d];
        a[4 + i] = As[(64 + ty * 4 + i) * PADL + d];
        b[i]     = Ws[(tx * 4 + i) * PADL + d];
        b[4 + i] = Ws[(64 + tx * 4 + i) * PADL + d];
      }
#pragma unroll
      for (int i = 0; i < 8; ++i)
#pragma unroll
        for (int j = 0; j < 8; ++j) acc[i][j] = fmaf(a[i], b[j], acc[i][j]);
    }
  }

  float sc[8];
  int cols[8];
#pragma unroll
  for (int j = 0; j < 8; ++j) {
    int c = (j < 4) ? tx * 4 + j : 64 + tx * 4 + (j - 4);
    cols[j] = k0 + c;
    sc[j] = wsq[cols[j]];
  }
#pragma unroll
  for (int i = 0; i < 8; ++i) {
    int r = (i < 4) ? ty * 4 + i : 64 + ty * 4 + (i - 4);
    unsigned long long bv = ~0ull;
#pragma unroll
    for (int j = 0; j < 8; ++j) {
      float score = fmaf(-2.0f, acc[i][j], sc[j]);
      unsigned u = __float_as_uint(score);
      u ^= (unsigned)(((int)u >> 31) | 0x80000000);
      unsigned long long p = ((unsigned long long)u << 32) | (unsigned)cols[j];
      bv = p < bv ? p : bv;
    }
    atomicMin(&best[r], bv);
  }
  __syncthreads();
  if (tid < TM) atomicMin(&packed[m0 + tid], best[tid]);
}

// ---------------- K3: indices + counts + z_q gather + loss + embed scatter ------
__global__ __launch_bounds__(256) void k_scatter(float* __restrict__ zt,
                                                 const float* __restrict__ w,
                                                 const unsigned long long* __restrict__ packed,
                                                 float* __restrict__ emb_out,
                                                 float* __restrict__ loss_sum,
                                                 float* __restrict__ out3,
                                                 float* __restrict__ counts) {
  int n = blockIdx.x, d = threadIdx.x;
  int k = (int)(packed[n] & 0xFFFFFFFFull) & (KC - 1);
  if (d == 0) {
    out3[n] = (float)k;
    atomicAdd(&counts[k], 1.0f);
  }
  float zv = zt[(size_t)n * DIM + d];
  float wv = w[(size_t)k * DIM + d];
  float diff = wv - zv;                       // z_q - z_perm
  zt[(size_t)n * DIM + d] = zv + diff;        // straight-through
  atomicAdd(&emb_out[(size_t)k * DIM + d], ONEMDECAY * zv);
  float v = diff * diff;
#pragma unroll
  for (int off = 32; off; off >>= 1) v += __shfl_down(v, off);
  __shared__ float red[4];
  if ((threadIdx.x & 63) == 0) red[threadIdx.x >> 6] = v;
  __syncthreads();
  if (threadIdx.x == 0) atomicAdd(loss_sum, red[0] + red[1] + red[2] + red[3]);
}

// ---------------- K4a: new_cluster_size, n_sum, perplexity partial --------------
__global__ void k_cs(const float* __restrict__ cs, const float* __restrict__ counts,
                     float* __restrict__ out5, float* __restrict__ scal) {
  int k = blockIdx.x * 256 + threadIdx.x;
  float c = counts[k];
  float ncs = cs[k] * DECAYF + ONEMDECAY * c;
  out5[k] = ncs;
  float p = c * (1.0f / (float)NZ);
  float t = p * logf(p + 1e-10f);
#pragma unroll
  for (int off = 32; off; off >>= 1) {
    ncs += __shfl_down(ncs, off);
    t += __shfl_down(t, off);
  }
  __shared__ float r1[4], r2[4];
  if ((threadIdx.x & 63) == 0) { r1[threadIdx.x >> 6] = ncs; r2[threadIdx.x >> 6] = t; }
  __syncthreads();
  if (threadIdx.x == 0) {
    atomicAdd(&scal[1], r1[0] + r1[1] + r1[2] + r1[3]);
    atomicAdd(&scal[2], r2[0] + r2[1] + r2[2] + r2[3]);
  }
}

// ---------------- K4b: new_weight + scalars -------------------------------------
__global__ void k_final(const float* __restrict__ emb_out, const float* __restrict__ out5,
                        const float* __restrict__ scal, float* __restrict__ out4,
                        float* __restrict__ out1, float* __restrict__ out2) {
  size_t i = (size_t)blockIdx.x * 256 + threadIdx.x;
  float n = scal[1];
  int k = (int)(i >> 8);
  float ncs = out5[k];
  float smoothed = (ncs + EPSF) / (n + (float)KC * EPSF) * n;
  out4[i] = emb_out[i] / smoothed;
  if (i == 0) {
    out1[0] = BETAF * scal[0] / (float)(NZ * DIM);
    out2[0] = expf(-scal[2]);
  }
}

extern "C" void kernel_launch(void* const* d_in, const int* in_sizes, int n_in,
                              void* d_out, int out_size, void* d_ws, size_t ws_size,
                              hipStream_t stream) {
  const float* z  = (const float*)d_in[0];
  const float* w  = (const float*)d_in[1];
  const float* cs = (const float*)d_in[2];
  const float* ea = (const float*)d_in[3];
  float* out = (float*)d_out;
  float* ws  = (float*)d_ws;

  if (ws_size < (size_t)WS_FLOATS_OLD * sizeof(float)) return;  // fail loudly
  const bool use_mfma = ws_size >= (size_t)WS_FLOATS_NEW * sizeof(float);

  float* zt      = ws + W_ZT;
  float* wsq     = ws + W_WSQ;
  float* counts  = ws + W_CNT;
  float* scal    = ws + W_SCAL;
  unsigned long long* packed = (unsigned long long*)(ws + W_PACKED);
  _Float16* Acat = (_Float16*)(ws + W_ACAT);
  _Float16* Bcat = (_Float16*)(ws + W_BCAT);

  float* out0 = out + O_ZQ;
  float* out1 = out + O_LOSS;
  float* out2 = out + O_PERP;
  float* out3 = out + O_IDX;
  float* out4 = out + O_NW;
  float* out5 = out + O_NCS;
  float* out6 = out + O_NEA;

  hipMemsetAsync(counts, 0, (16384 + 4) * sizeof(float), stream);   // counts + scal
  hipMemsetAsync(packed, 0xFF, (size_t)NZ * sizeof(unsigned long long), stream);

  if (use_mfma) {
    k_prep_fused<true><<<KC / 4 + 512, 256, 0, stream>>>(z, w, ea, zt, Acat, wsq, Bcat, out6);
    k_argmin_mfma<<<(KC / GBN) * (NZ / GBM), 512, 0, stream>>>(Acat, Bcat, wsq, packed);
  } else {
    k_prep_fused<false><<<KC / 4 + 512, 256, 0, stream>>>(z, w, ea, zt, Acat, wsq, Bcat, out6);
    k_argmin_fp32<<<dim3(KC / TN, NZ / TM), 256, 0, stream>>>(zt, w, wsq, packed);
  }
  k_scatter<<<NZ, 256, 0, stream>>>(zt, w, packed, out6, scal, out3, counts);
  k_cs<<<KC / 256, 256, 0, stream>>>(cs, counts, out5, scal);
  k_final<<<(KC * DIM) / 256, 256, 0, stream>>>(out6, out5, scal, out4, out1, out2);
  k_transpose_out<<<dim3(16, 4, NB), 256, 0, stream>>>(zt, out0);
}

// Round 12
// 390.229 us; speedup vs baseline: 1.0339x; 1.0339x over previous
//
#include <hip/hip_runtime.h>

// Problem constants (from setup_inputs): z (8,256,32,32), weight (16384,256)
#define NB   8
#define DIM  256
#define HW   1024          // 32*32
#define NZ   8192          // NB*HW flattened z rows
#define KC   16384         // codebook entries
#define DECAYF 0.99f
#define ONEMDECAY 0.01f
#define EPSF 1e-5f
#define BETAF 0.25f
// logical K = 768 ([ah|al|ah].[bh|bh|bl]); physical layout is dedup'd:
// Acat = [ah|al] (512), Bcat = [bh|bl] (512); segment->phys remap in STAGE.
#define APHYS 512

typedef _Float16 half8 __attribute__((ext_vector_type(8)));
typedef _Float16 half4 __attribute__((ext_vector_type(4)));
typedef float floatx4 __attribute__((ext_vector_type(4)));

// Output offsets (floats) in d_out, in reference return order
#define O_ZQ   0u
#define O_LOSS 2097152u
#define O_PERP 2097153u
#define O_IDX  2097154u
#define O_NW   2105346u
#define O_NCS  6299650u
#define O_NEA  6316034u

// ws layout (floats)
#define W_ZT     0u          // 8192*256 fp32
#define W_WSQ    2097152u    // 16384
#define W_CNT    2113536u    // 16384           (zeroed)
#define W_SCAL   2129920u    // 4: [0]=loss [1]=n_sum [2]=plogp (zeroed)
#define W_PACKED 2129924u    // 8192 u64 (byte off %8==0) (memset 0xFF)
#define W_ACAT   2146308u    // 8192*512 f16  (byte off %16==0)
#define W_BCAT   4243460u    // 16384*512 f16 (byte off %16==0)
#define WS_FLOATS_OLD 2146308u
#define WS_FLOATS_NEW 8437764u

// ---------------- K0 (fused): prep (wsq + Bcat + out6) AND transpose (zt + Acat)
// Independent streams fused into one launch: blocks [0, KC/4) do prep,
// blocks [KC/4, KC/4+512) do the z transpose.
template <bool SPLIT>
__global__ void k_prep_fused(const float* __restrict__ z, const float* __restrict__ w,
                             const float* __restrict__ ea, float* __restrict__ zt,
                             _Float16* __restrict__ Acat, float* __restrict__ wsq,
                             _Float16* __restrict__ Bcat, float* __restrict__ out6) {
  __shared__ float tile[64][65];
  if (blockIdx.x < KC / 4) {
    int wave = threadIdx.x >> 6, lane = threadIdx.x & 63;
    int k = blockIdx.x * 4 + wave;
    float4 v = *(const float4*)&w[(size_t)k * DIM + lane * 4];
    float s = v.x * v.x + v.y * v.y + v.z * v.z + v.w * v.w;
#pragma unroll
    for (int off = 32; off; off >>= 1) s += __shfl_xor(s, off);
    if (lane == 0) wsq[k] = s;
    if (SPLIT) {
      half4 h = { (_Float16)v.x, (_Float16)v.y, (_Float16)v.z, (_Float16)v.w };
      half4 lo = { (_Float16)(v.x - (float)h.x), (_Float16)(v.y - (float)h.y),
                   (_Float16)(v.z - (float)h.z), (_Float16)(v.w - (float)h.w) };
      size_t bbase = (size_t)k * APHYS + lane * 4;
      *(half4*)&Bcat[bbase] = h;          // phys seg0 = bh
      *(half4*)&Bcat[bbase + 256] = lo;   // phys seg1 = bl
    }
    float4 e = *(const float4*)&ea[(size_t)k * DIM + lane * 4];
    float4 o = { DECAYF * e.x, DECAYF * e.y, DECAYF * e.z, DECAYF * e.w };
    *(float4*)&out6[(size_t)k * DIM + lane * 4] = o;
  } else {
    int flat = blockIdx.x - KC / 4;
    int hwb = (flat & 15) * 64, db = ((flat >> 4) & 3) * 64, b = flat >> 6;
    int lane = threadIdx.x & 63, sub = threadIdx.x >> 6;
#pragma unroll
    for (int i = 0; i < 16; ++i) {
      int dof = sub * 16 + i;
      tile[dof][lane] = z[((size_t)(b * DIM + db + dof)) * HW + hwb + lane];
    }
    __syncthreads();
#pragma unroll
    for (int i = 0; i < 16; ++i) {
      int hwof = sub * 16 + i;
      int n = b * HW + hwb + hwof;
      float val = tile[lane][hwof];
      zt[(size_t)n * DIM + db + lane] = val;
      if (SPLIT) {
        _Float16 h = (_Float16)val;
        _Float16 lo = (_Float16)(val - (float)h);
        size_t abase = (size_t)n * APHYS + db + lane;
        Acat[abase] = h;          // phys seg0 = ah
        Acat[abase + 256] = lo;   // phys seg1 = al
      }
    }
  }
}

// ---------------- K2: 128x256 MFMA distance GEMM + fused argmin ------------------
// 8 waves (2M x 4N), per-wave output 64x64 (acc 64 regs -> 4 waves/SIMD ->
// 2 blocks/CU, 48 KB single-buffered LDS; cross-block overlap hides staging).
// Runtime K-loop (R10-verified): full unroll spills to scratch (R11, 119 MB
// WRITE_SIZE) under the launch_bounds(512,4) register cap.
#define GBM 128
#define GBN 256
#define GBK 64
#define NSTEP 12            // logical K = 768

__device__ __forceinline__ void gload16(const _Float16* g, _Float16* lds) {
  __builtin_amdgcn_global_load_lds((__attribute__((address_space(1))) void*)g,
                                   (__attribute__((address_space(3))) void*)lds, 16, 0, 0);
}

#define WAITVM0   asm volatile("s_waitcnt vmcnt(0)" ::: "memory")
#define WAITLGKM0 asm volatile("s_waitcnt lgkmcnt(0)" ::: "memory")
#define BAR       __builtin_amdgcn_s_barrier()

__global__ __launch_bounds__(512, 4) void k_argmin_mfma(const _Float16* __restrict__ Acat,
                                                        const _Float16* __restrict__ Bcat,
                                                        const float* __restrict__ wsq,
                                                        unsigned long long* __restrict__ packed) {
  __shared__ __align__(16) _Float16 As[GBM * GBK];   // 16 KB
  __shared__ __align__(16) _Float16 Bs[GBN * GBK];   // 32 KB  (total 48 KB)
  const int tid = threadIdx.x;
  const int w = tid >> 6, l = tid & 63;
  const int lr = l & 15, lc = l >> 4;
  const int wr = w >> 2, wc = w & 3;   // 2 x 4 wave grid, 64x64 per wave
  // XCD ownership: xcd = bid&7 owns 8 n-panels (L2-resident Bcat slice);
  // m-major order within the XCD reuses each A panel across its n-panels.
  const int bid = (int)blockIdx.x;
  const int xcd = bid & 7, local = bid >> 3;           // 4096 blocks total
  const int m0 = (local >> 3) * GBM;                   // 64 m-tiles
  const int n0 = (xcd * 8 + (local & 7)) * GBN;        // 64 n-tiles

  floatx4 acc[4][4];
#pragma unroll
  for (int i = 0; i < 4; ++i)
#pragma unroll
    for (int j = 0; j < 4; ++j) acc[i][j] = (floatx4){0.f, 0.f, 0.f, 0.f};

  // staging: LDS linear dest; global source pre-swizzled chunk^(row&7) so the
  // frag ds_read_b128 (row stride 128B) is bank-conflict-free.
  const int srow = (l >> 3);
  const int schk = (l & 7);

  // 6 gloads per thread per K-step: 2 A row-groups + 4 B row-groups of 8 rows.
  // logical step -> physical offsets: seg = STEP>>2 (0:ah.bh 1:al.bh 2:ah.bl)
#define STAGE(STEP)                                                               \
  {                                                                               \
    const int seg_ = (STEP) >> 2, ksub_ = (STEP) & 3;                             \
    const int aoff_ = (seg_ == 1 ? 256 : 0) + ksub_ * 64;                         \
    const int boff_ = (seg_ == 2 ? 256 : 0) + ksub_ * 64;                         \
    _Pragma("unroll")                                                             \
    for (int c = 0; c < 2; ++c) {                                                 \
      int row = (w * 2 + c) * 8 + srow;                                           \
      int sc_ = schk ^ (row & 7);                                                 \
      gload16(Acat + (size_t)(m0 + row) * APHYS + aoff_ + sc_ * 8,                \
              &As[(w * 2 + c) * 512]);                                            \
    }                                                                             \
    _Pragma("unroll")                                                             \
    for (int c = 0; c < 4; ++c) {                                                 \
      int row = (w * 4 + c) * 8 + srow;                                           \
      int sc_ = schk ^ (row & 7);                                                 \
      gload16(Bcat + (size_t)(n0 + row) * APHYS + boff_ + sc_ * 8,                \
              &Bs[(w * 4 + c) * 512]);                                            \
    }                                                                             \
  }

  for (int t = 0; t < NSTEP; ++t) {
    STAGE(t);
    WAITVM0;                 // my 6 stage-loads landed
    BAR;                     // everyone's landed -> tile valid
#pragma unroll
    for (int kk = 0; kk < 2; ++kk) {
      half8 af[4], bf[4];
#pragma unroll
      for (int mi = 0; mi < 4; ++mi) {
        int row = wr * 64 + mi * 16 + lr;
        int ch = (kk * 4 + lc) ^ (row & 7);
        af[mi] = *(const half8*)&As[row * GBK + ch * 8];
      }
#pragma unroll
      for (int ni = 0; ni < 4; ++ni) {
        int row = wc * 64 + ni * 16 + lr;
        int ch = (kk * 4 + lc) ^ (row & 7);
        bf[ni] = *(const half8*)&Bs[row * GBK + ch * 8];
      }
#pragma unroll
      for (int mi = 0; mi < 4; ++mi)
#pragma unroll
        for (int ni = 0; ni < 4; ++ni)
          acc[mi][ni] = __builtin_amdgcn_mfma_f32_16x16x32_f16(af[mi], bf[ni], acc[mi][ni], 0, 0, 0);
    }
    WAITLGKM0;               // my LDS reads retired
    BAR;                     // everyone done reading -> safe to overwrite
  }
#undef STAGE

  // epilogue: per-row argmin. C layout: col = lane&15, row = (lane>>4)*4 + reg.
  // best[] aliases the A buffer (final BAR above bounds all reads).
  unsigned long long* best = (unsigned long long*)&As[0];
  if (tid < GBM) best[tid] = ~0ull;
  __syncthreads();
  float sc4[4];
  int col4[4];
#pragma unroll
  for (int ni = 0; ni < 4; ++ni) {
    col4[ni] = n0 + wc * 64 + ni * 16 + lr;
    sc4[ni] = wsq[col4[ni]];
  }
#pragma unroll
  for (int mi = 0; mi < 4; ++mi) {
#pragma unroll
    for (int r = 0; r < 4; ++r) {
      unsigned long long bv = ~0ull;
#pragma unroll
      for (int ni = 0; ni < 4; ++ni) {
        float score = fmaf(-2.0f, acc[mi][ni][r], sc4[ni]);
        unsigned u = __float_as_uint(score);
        u ^= (unsigned)(((int)u >> 31) | 0x80000000);  // monotonic float->uint
        unsigned long long p = ((unsigned long long)u << 32) | (unsigned)col4[ni];
        bv = p < bv ? p : bv;
      }
#pragma unroll
      for (int off = 1; off < 16; off <<= 1) {
        unsigned long long o = __shfl_xor(bv, off);
        bv = o < bv ? o : bv;
      }
      if (lr == 0) atomicMin(&best[wr * 64 + mi * 16 + lc * 4 + r], bv);
    }
  }
  __syncthreads();
  if (tid < GBM) atomicMin(&packed[m0 + tid], best[tid]);
}

// ---------------- Fallback fp32 GEMM+argmin -------------------------------------
#define TM 128
#define TN 128
#define DK 32
#define PADL 33
__global__ __launch_bounds__(256) void k_argmin_fp32(const float* __restrict__ zt,
                                                     const float* __restrict__ w,
                                                     const float* __restrict__ wsq,
                                                     unsigned long long* __restrict__ packed) {
  __shared__ float As[TM * PADL];
  __shared__ float Ws[TN * PADL];
  __shared__ unsigned long long best[TM];
  const int tid = threadIdx.x;
  const int k0 = blockIdx.x * TN, m0 = blockIdx.y * TM;
  if (tid < TM) best[tid] = ~0ull;
  const int tx = tid & 15, ty = tid >> 4;
  const int mrow = tid & 127;
  const int q = (tid >> 7) * 16;

  float acc[8][8];
#pragma unroll
  for (int i = 0; i < 8; ++i)
#pragma unroll
    for (int j = 0; j < 8; ++j) acc[i][j] = 0.0f;

  for (int dbase = 0; dbase < DIM; dbase += DK) {
    __syncthreads();
    const float* za = &zt[(size_t)(m0 + mrow) * DIM + dbase + q];
    const float* wa = &w[(size_t)(k0 + mrow) * DIM + dbase + q];
    float4 a0 = *(const float4*)(za + 0), a1 = *(const float4*)(za + 4);
    float4 a2 = *(const float4*)(za + 8), a3 = *(const float4*)(za + 12);
    float4 b0 = *(const float4*)(wa + 0), b1 = *(const float4*)(wa + 4);
    float4 b2 = *(const float4*)(wa + 8), b3 = *(const float4*)(wa + 12);
    float* Ap = &As[mrow * PADL + q];
    float* Wp = &Ws[mrow * PADL + q];
    Ap[0] = a0.x; Ap[1] = a0.y; Ap[2] = a0.z; Ap[3] = a0.w;
    Ap[4] = a1.x; Ap[5] = a1.y; Ap[6] = a1.z; Ap[7] = a1.w;
    Ap[8] = a2.x; Ap[9] = a2.y; Ap[10] = a2.z; Ap[11] = a2.w;
    Ap[12] = a3.x; Ap[13] = a3.y; Ap[14] = a3.z; Ap[15] = a3.w;
    Wp[0] = b0.x; Wp[1] = b0.y; Wp[2] = b0.z; Wp[3] = b0.w;
    Wp[4] = b1.x; Wp[5] = b1.y; Wp[6] = b1.z; Wp[7] = b1.w;
    Wp[8] = b2.x; Wp[9] = b2.y; Wp[10] = b2.z; Wp[11] = b2.w;
    Wp[12] = b3.x; Wp[13] = b3.y; Wp[14] = b3.z; Wp[15] = b3.w;
    __syncthreads();
#pragma unroll
    for (int d = 0; d < DK; ++d) {
      float a[8], b[8];
#pragma unroll
      for (int i = 0; i < 4; ++i) {
        a[i]     = As[(ty * 4 + i) * PADL + d];
        a[4 + i] = As[(64 + ty * 4 + i) * PADL + d];
        b[i]     = Ws[(tx * 4 + i) * PADL + d];
        b[4 + i] = Ws[(64 + tx * 4 + i) * PADL + d];
      }
#pragma unroll
      for (int i = 0; i < 8; ++i)
#pragma unroll
        for (int j = 0; j < 8; ++j) acc[i][j] = fmaf(a[i], b[j], acc[i][j]);
    }
  }

  float sc[8];
  int cols[8];
#pragma unroll
  for (int j = 0; j < 8; ++j) {
    int c = (j < 4) ? tx * 4 + j : 64 + tx * 4 + (j - 4);
    cols[j] = k0 + c;
    sc[j] = wsq[cols[j]];
  }
#pragma unroll
  for (int i = 0; i < 8; ++i) {
    int r = (i < 4) ? ty * 4 + i : 64 + ty * 4 + (i - 4);
    unsigned long long bv = ~0ull;
#pragma unroll
    for (int j = 0; j < 8; ++j) {
      float score = fmaf(-2.0f, acc[i][j], sc[j]);
      unsigned u = __float_as_uint(score);
      u ^= (unsigned)(((int)u >> 31) | 0x80000000);
      unsigned long long p = ((unsigned long long)u << 32) | (unsigned)cols[j];
      bv = p < bv ? p : bv;
    }
    atomicMin(&best[r], bv);
  }
  __syncthreads();
  if (tid < TM) atomicMin(&packed[m0 + tid], best[tid]);
}

// ---------------- K3: indices + counts + z_q gather + loss + embed scatter ------
__global__ __launch_bounds__(256) void k_scatter(float* __restrict__ zt,
                                                 const float* __restrict__ w,
                                                 const unsigned long long* __restrict__ packed,
                                                 float* __restrict__ emb_out,
                                                 float* __restrict__ loss_sum,
                                                 float* __restrict__ out3,
                                                 float* __restrict__ counts) {
  int n = blockIdx.x, d = threadIdx.x;
  int k = (int)(packed[n] & 0xFFFFFFFFull) & (KC - 1);
  if (d == 0) {
    out3[n] = (float)k;
    atomicAdd(&counts[k], 1.0f);
  }
  float zv = zt[(size_t)n * DIM + d];
  float wv = w[(size_t)k * DIM + d];
  float diff = wv - zv;                       // z_q - z_perm
  zt[(size_t)n * DIM + d] = zv + diff;        // straight-through
  atomicAdd(&emb_out[(size_t)k * DIM + d], ONEMDECAY * zv);
  float v = diff * diff;
#pragma unroll
  for (int off = 32; off; off >>= 1) v += __shfl_down(v, off);
  __shared__ float red[4];
  if ((threadIdx.x & 63) == 0) red[threadIdx.x >> 6] = v;
  __syncthreads();
  if (threadIdx.x == 0) atomicAdd(loss_sum, red[0] + red[1] + red[2] + red[3]);
}

// ---------------- K4a: new_cluster_size, n_sum, perplexity partial --------------
__global__ void k_cs(const float* __restrict__ cs, const float* __restrict__ counts,
                     float* __restrict__ out5, float* __restrict__ scal) {
  int k = blockIdx.x * 256 + threadIdx.x;
  float c = counts[k];
  float ncs = cs[k] * DECAYF + ONEMDECAY * c;
  out5[k] = ncs;
  float p = c * (1.0f / (float)NZ);
  float t = p * logf(p + 1e-10f);
#pragma unroll
  for (int off = 32; off; off >>= 1) {
    ncs += __shfl_down(ncs, off);
    t += __shfl_down(t, off);
  }
  __shared__ float r1[4], r2[4];
  if ((threadIdx.x & 63) == 0) { r1[threadIdx.x >> 6] = ncs; r2[threadIdx.x >> 6] = t; }
  __syncthreads();
  if (threadIdx.x == 0) {
    atomicAdd(&scal[1], r1[0] + r1[1] + r1[2] + r1[3]);
    atomicAdd(&scal[2], r2[0] + r2[1] + r2[2] + r2[3]);
  }
}

// ---------------- K4b (fused): new_weight + scalars AND transpose_out -----------
// blocks [0, KC*DIM/256) do new_weight; blocks [KC*DIM/256, +512) do the
// zt -> out0 transpose (independent outputs, both deps ready after k_cs).
__global__ void k_final_fused(const float* __restrict__ emb_out, const float* __restrict__ out5,
                              const float* __restrict__ scal, const float* __restrict__ zt,
                              float* __restrict__ out4, float* __restrict__ out1,
                              float* __restrict__ out2, float* __restrict__ out0) {
  __shared__ float tile[64][65];
  if (blockIdx.x < (KC * DIM) / 256) {
    size_t i = (size_t)blockIdx.x * 256 + threadIdx.x;
    float n = scal[1];
    int k = (int)(i >> 8);
    float ncs = out5[k];
    float smoothed = (ncs + EPSF) / (n + (float)KC * EPSF) * n;
    out4[i] = emb_out[i] / smoothed;
    if (i == 0) {
      out1[0] = BETAF * scal[0] / (float)(NZ * DIM);
      out2[0] = expf(-scal[2]);
    }
  } else {
    int flat = blockIdx.x - (KC * DIM) / 256;
    int hwb = (flat & 15) * 64, db = ((flat >> 4) & 3) * 64, b = flat >> 6;
    int lane = threadIdx.x & 63, sub = threadIdx.x >> 6;
#pragma unroll
    for (int i = 0; i < 16; ++i) {
      int hwof = sub * 16 + i;
      tile[hwof][lane] = zt[((size_t)(b * HW + hwb + hwof)) * DIM + db + lane];
    }
    __syncthreads();
#pragma unroll
    for (int i = 0; i < 16; ++i) {
      int dof = sub * 16 + i;
      out0[((size_t)(b * DIM + db + dof)) * HW + hwb + lane] = tile[lane][dof];
    }
  }
}

extern "C" void kernel_launch(void* const* d_in, const int* in_sizes, int n_in,
                              void* d_out, int out_size, void* d_ws, size_t ws_size,
                              hipStream_t stream) {
  const float* z  = (const float*)d_in[0];
  const float* w  = (const float*)d_in[1];
  const float* cs = (const float*)d_in[2];
  const float* ea = (const float*)d_in[3];
  float* out = (float*)d_out;
  float* ws  = (float*)d_ws;

  if (ws_size < (size_t)WS_FLOATS_OLD * sizeof(float)) return;  // fail loudly
  const bool use_mfma = ws_size >= (size_t)WS_FLOATS_NEW * sizeof(float);

  float* zt      = ws + W_ZT;
  float* wsq     = ws + W_WSQ;
  float* counts  = ws + W_CNT;
  float* scal    = ws + W_SCAL;
  unsigned long long* packed = (unsigned long long*)(ws + W_PACKED);
  _Float16* Acat = (_Float16*)(ws + W_ACAT);
  _Float16* Bcat = (_Float16*)(ws + W_BCAT);

  float* out0 = out + O_ZQ;
  float* out1 = out + O_LOSS;
  float* out2 = out + O_PERP;
  float* out3 = out + O_IDX;
  float* out4 = out + O_NW;
  float* out5 = out + O_NCS;
  float* out6 = out + O_NEA;

  hipMemsetAsync(counts, 0, (16384 + 4) * sizeof(float), stream);   // counts + scal
  hipMemsetAsync(packed, 0xFF, (size_t)NZ * sizeof(unsigned long long), stream);

  if (use_mfma) {
    k_prep_fused<true><<<KC / 4 + 512, 256, 0, stream>>>(z, w, ea, zt, Acat, wsq, Bcat, out6);
    k_argmin_mfma<<<(KC / GBN) * (NZ / GBM), 512, 0, stream>>>(Acat, Bcat, wsq, packed);
  } else {
    k_prep_fused<false><<<KC / 4 + 512, 256, 0, stream>>>(z, w, ea, zt, Acat, wsq, Bcat, out6);
    k_argmin_fp32<<<dim3(KC / TN, NZ / TM), 256, 0, stream>>>(zt, w, wsq, packed);
  }
  k_scatter<<<NZ, 256, 0, stream>>>(zt, w, packed, out6, scal, out3, counts);
  k_cs<<<KC / 256, 256, 0, stream>>>(cs, counts, out5, scal);
  k_final_fused<<<(KC * DIM) / 256 + 512, 256, 0, stream>>>(out6, out5, scal, zt,
                                                            out4, out1, out2, out0);
}

// Round 13
// 340.880 us; speedup vs baseline: 1.1835x; 1.1448x over previous
//
#include <hip/hip_runtime.h>

// Problem constants (from setup_inputs): z (8,256,32,32), weight (16384,256)
#define NB   8
#define DIM  256
#define HW   1024          // 32*32
#define NZ   8192          // NB*HW flattened z rows
#define KC   16384         // codebook entries
#define DECAYF 0.99f
#define ONEMDECAY 0.01f
#define EPSF 1e-5f
#define BETAF 0.25f
// logical K = 768 ([ah|al|ah].[bh|bh|bl]); physical layout is dedup'd:
// Acat = [ah|al] (512), Bcat = [bh|bl] (512); segment->phys remap in STAGE.
#define APHYS 512

typedef _Float16 half8 __attribute__((ext_vector_type(8)));
typedef _Float16 half4 __attribute__((ext_vector_type(4)));
typedef float floatx4 __attribute__((ext_vector_type(4)));

// Output offsets (floats) in d_out, in reference return order
#define O_ZQ   0u
#define O_LOSS 2097152u
#define O_PERP 2097153u
#define O_IDX  2097154u
#define O_NW   2105346u
#define O_NCS  6299650u
#define O_NEA  6316034u

// ws layout (floats)
#define W_ZT     0u          // 8192*256 fp32
#define W_WSQ    2097152u    // 16384
#define W_CNT    2113536u    // 16384           (zeroed)
#define W_SCAL   2129920u    // 4: [0]=loss [3]=sum_cs (zeroed)
#define W_PACKED 2129924u    // 8192 u64 (byte off %8==0) (memset 0xFF)
#define W_ACAT   2146308u    // 8192*512 f16  (byte off %16==0)
#define W_BCAT   4243460u    // 16384*512 f16 (byte off %16==0)
#define WS_FLOATS_OLD 2146308u
#define WS_FLOATS_NEW 8437764u

// ---------------- K0 (fused): prep (wsq+Bcat+out6) | transpose (zt+Acat) | sum_cs
// blocks [0,4096): w-prep; [4096,4608): z transpose; [4608,4672): sum(cs)->scal[3]
template <bool SPLIT>
__global__ void k_prep_fused(const float* __restrict__ z, const float* __restrict__ w,
                             const float* __restrict__ ea, const float* __restrict__ cs,
                             float* __restrict__ zt, _Float16* __restrict__ Acat,
                             float* __restrict__ wsq, _Float16* __restrict__ Bcat,
                             float* __restrict__ out6, float* __restrict__ scal) {
  __shared__ float tile[64][65];
  if (blockIdx.x < KC / 4) {
    int wave = threadIdx.x >> 6, lane = threadIdx.x & 63;
    int k = blockIdx.x * 4 + wave;
    float4 v = *(const float4*)&w[(size_t)k * DIM + lane * 4];
    float s = v.x * v.x + v.y * v.y + v.z * v.z + v.w * v.w;
#pragma unroll
    for (int off = 32; off; off >>= 1) s += __shfl_xor(s, off);
    if (lane == 0) wsq[k] = s;
    if (SPLIT) {
      half4 h = { (_Float16)v.x, (_Float16)v.y, (_Float16)v.z, (_Float16)v.w };
      half4 lo = { (_Float16)(v.x - (float)h.x), (_Float16)(v.y - (float)h.y),
                   (_Float16)(v.z - (float)h.z), (_Float16)(v.w - (float)h.w) };
      size_t bbase = (size_t)k * APHYS + lane * 4;
      *(half4*)&Bcat[bbase] = h;          // phys seg0 = bh
      *(half4*)&Bcat[bbase + 256] = lo;   // phys seg1 = bl
    }
    float4 e = *(const float4*)&ea[(size_t)k * DIM + lane * 4];
    float4 o = { DECAYF * e.x, DECAYF * e.y, DECAYF * e.z, DECAYF * e.w };
    *(float4*)&out6[(size_t)k * DIM + lane * 4] = o;
  } else if (blockIdx.x < KC / 4 + 512) {
    int flat = blockIdx.x - KC / 4;
    int hwb = (flat & 15) * 64, db = ((flat >> 4) & 3) * 64, b = flat >> 6;
    int lane = threadIdx.x & 63, sub = threadIdx.x >> 6;
#pragma unroll
    for (int i = 0; i < 16; ++i) {
      int dof = sub * 16 + i;
      tile[dof][lane] = z[((size_t)(b * DIM + db + dof)) * HW + hwb + lane];
    }
    __syncthreads();
#pragma unroll
    for (int i = 0; i < 16; ++i) {
      int hwof = sub * 16 + i;
      int n = b * HW + hwb + hwof;
      float val = tile[lane][hwof];
      zt[(size_t)n * DIM + db + lane] = val;
      if (SPLIT) {
        _Float16 h = (_Float16)val;
        _Float16 lo = (_Float16)(val - (float)h);
        size_t abase = (size_t)n * APHYS + db + lane;
        Acat[abase] = h;          // phys seg0 = ah
        Acat[abase + 256] = lo;   // phys seg1 = al
      }
    }
  } else {
    // sum(cluster_size) -> scal[3]  (input-only; enables n_sum without k_cs)
    int idx = (blockIdx.x - (KC / 4 + 512)) * 256 + threadIdx.x;
    float v = cs[idx];
#pragma unroll
    for (int off = 32; off; off >>= 1) v += __shfl_xor(v, off);
    __shared__ float r[4];
    if ((threadIdx.x & 63) == 0) r[threadIdx.x >> 6] = v;
    __syncthreads();
    if (threadIdx.x == 0) atomicAdd(&scal[3], r[0] + r[1] + r[2] + r[3]);
  }
}

// ---------------- K2: 128x256 MFMA distance GEMM + fused argmin ------------------
// 8 waves (2M x 4N), per-wave output 64x64 (acc 64 regs -> 4 waves/SIMD ->
// 2 blocks/CU, 48 KB single-buffered LDS; cross-block overlap hides staging).
// Runtime K-loop (R10/R12-verified): full unroll spills (R11, 119 MB scratch)
// under the launch_bounds(512,4) 128-reg/wave cap (acc 64 + arch 60 = 124).
#define GBM 128
#define GBN 256
#define GBK 64
#define NSTEP 12            // logical K = 768

__device__ __forceinline__ void gload16(const _Float16* g, _Float16* lds) {
  __builtin_amdgcn_global_load_lds((__attribute__((address_space(1))) void*)g,
                                   (__attribute__((address_space(3))) void*)lds, 16, 0, 0);
}

#define WAITVM0   asm volatile("s_waitcnt vmcnt(0)" ::: "memory")
#define WAITLGKM0 asm volatile("s_waitcnt lgkmcnt(0)" ::: "memory")
#define BAR       __builtin_amdgcn_s_barrier()

__global__ __launch_bounds__(512, 4) void k_argmin_mfma(const _Float16* __restrict__ Acat,
                                                        const _Float16* __restrict__ Bcat,
                                                        const float* __restrict__ wsq,
                                                        unsigned long long* __restrict__ packed) {
  __shared__ __align__(16) _Float16 As[GBM * GBK];   // 16 KB
  __shared__ __align__(16) _Float16 Bs[GBN * GBK];   // 32 KB  (total 48 KB)
  const int tid = threadIdx.x;
  const int w = tid >> 6, l = tid & 63;
  const int lr = l & 15, lc = l >> 4;
  const int wr = w >> 2, wc = w & 3;   // 2 x 4 wave grid, 64x64 per wave
  // XCD ownership: xcd = bid&7 owns 8 n-panels (L2-resident Bcat slice);
  // m-major order within the XCD reuses each A panel across its n-panels.
  const int bid = (int)blockIdx.x;
  const int xcd = bid & 7, local = bid >> 3;           // 4096 blocks total
  const int m0 = (local >> 3) * GBM;                   // 64 m-tiles
  const int n0 = (xcd * 8 + (local & 7)) * GBN;        // 64 n-tiles

  floatx4 acc[4][4];
#pragma unroll
  for (int i = 0; i < 4; ++i)
#pragma unroll
    for (int j = 0; j < 4; ++j) acc[i][j] = (floatx4){0.f, 0.f, 0.f, 0.f};

  // staging: LDS linear dest; global source pre-swizzled chunk^(row&7) so the
  // frag ds_read_b128 (row stride 128B) is bank-conflict-free.
  const int srow = (l >> 3);
  const int schk = (l & 7);

  // 6 gloads per thread per K-step: 2 A row-groups + 4 B row-groups of 8 rows.
  // logical step -> physical offsets: seg = STEP>>2 (0:ah.bh 1:al.bh 2:ah.bl)
#define STAGE(STEP)                                                               \
  {                                                                               \
    const int seg_ = (STEP) >> 2, ksub_ = (STEP) & 3;                             \
    const int aoff_ = (seg_ == 1 ? 256 : 0) + ksub_ * 64;                         \
    const int boff_ = (seg_ == 2 ? 256 : 0) + ksub_ * 64;                         \
    _Pragma("unroll")                                                             \
    for (int c = 0; c < 2; ++c) {                                                 \
      int row = (w * 2 + c) * 8 + srow;                                           \
      int sc_ = schk ^ (row & 7);                                                 \
      gload16(Acat + (size_t)(m0 + row) * APHYS + aoff_ + sc_ * 8,                \
              &As[(w * 2 + c) * 512]);                                            \
    }                                                                             \
    _Pragma("unroll")                                                             \
    for (int c = 0; c < 4; ++c) {                                                 \
      int row = (w * 4 + c) * 8 + srow;                                           \
      int sc_ = schk ^ (row & 7);                                                 \
      gload16(Bcat + (size_t)(n0 + row) * APHYS + boff_ + sc_ * 8,                \
              &Bs[(w * 4 + c) * 512]);                                            \
    }                                                                             \
  }

  for (int t = 0; t < NSTEP; ++t) {
    STAGE(t);
    WAITVM0;                 // my 6 stage-loads landed
    BAR;                     // everyone's landed -> tile valid
#pragma unroll
    for (int kk = 0; kk < 2; ++kk) {
      half8 af[4], bf[4];
#pragma unroll
      for (int mi = 0; mi < 4; ++mi) {
        int row = wr * 64 + mi * 16 + lr;
        int ch = (kk * 4 + lc) ^ (row & 7);
        af[mi] = *(const half8*)&As[row * GBK + ch * 8];
      }
#pragma unroll
      for (int ni = 0; ni < 4; ++ni) {
        int row = wc * 64 + ni * 16 + lr;
        int ch = (kk * 4 + lc) ^ (row & 7);
        bf[ni] = *(const half8*)&Bs[row * GBK + ch * 8];
      }
#pragma unroll
      for (int mi = 0; mi < 4; ++mi)
#pragma unroll
        for (int ni = 0; ni < 4; ++ni)
          acc[mi][ni] = __builtin_amdgcn_mfma_f32_16x16x32_f16(af[mi], bf[ni], acc[mi][ni], 0, 0, 0);
    }
    WAITLGKM0;               // my LDS reads retired
    BAR;                     // everyone done reading -> safe to overwrite
  }
#undef STAGE

  // epilogue: per-row argmin. C layout: col = lane&15, row = (lane>>4)*4 + reg.
  // best[] aliases the A buffer (final BAR above bounds all reads).
  unsigned long long* best = (unsigned long long*)&As[0];
  if (tid < GBM) best[tid] = ~0ull;
  __syncthreads();
  float sc4[4];
  int col4[4];
#pragma unroll
  for (int ni = 0; ni < 4; ++ni) {
    col4[ni] = n0 + wc * 64 + ni * 16 + lr;
    sc4[ni] = wsq[col4[ni]];
  }
#pragma unroll
  for (int mi = 0; mi < 4; ++mi) {
#pragma unroll
    for (int r = 0; r < 4; ++r) {
      unsigned long long bv = ~0ull;
#pragma unroll
      for (int ni = 0; ni < 4; ++ni) {
        float score = fmaf(-2.0f, acc[mi][ni][r], sc4[ni]);
        unsigned u = __float_as_uint(score);
        u ^= (unsigned)(((int)u >> 31) | 0x80000000);  // monotonic float->uint
        unsigned long long p = ((unsigned long long)u << 32) | (unsigned)col4[ni];
        bv = p < bv ? p : bv;
      }
#pragma unroll
      for (int off = 1; off < 16; off <<= 1) {
        unsigned long long o = __shfl_xor(bv, off);
        bv = o < bv ? o : bv;
      }
      if (lr == 0) atomicMin(&best[wr * 64 + mi * 16 + lc * 4 + r], bv);
    }
  }
  __syncthreads();
  if (tid < GBM) atomicMin(&packed[m0 + tid], best[tid]);
}

// ---------------- Fallback fp32 GEMM+argmin -------------------------------------
#define TM 128
#define TN 128
#define DK 32
#define PADL 33
__global__ __launch_bounds__(256) void k_argmin_fp32(const float* __restrict__ zt,
                                                     const float* __restrict__ w,
                                                     const float* __restrict__ wsq,
                                                     unsigned long long* __restrict__ packed) {
  __shared__ float As[TM * PADL];
  __shared__ float Ws[TN * PADL];
  __shared__ unsigned long long best[TM];
  const int tid = threadIdx.x;
  const int k0 = blockIdx.x * TN, m0 = blockIdx.y * TM;
  if (tid < TM) best[tid] = ~0ull;
  const int tx = tid & 15, ty = tid >> 4;
  const int mrow = tid & 127;
  const int q = (tid >> 7) * 16;

  float acc[8][8];
#pragma unroll
  for (int i = 0; i < 8; ++i)
#pragma unroll
    for (int j = 0; j < 8; ++j) acc[i][j] = 0.0f;

  for (int dbase = 0; dbase < DIM; dbase += DK) {
    __syncthreads();
    const float* za = &zt[(size_t)(m0 + mrow) * DIM + dbase + q];
    const float* wa = &w[(size_t)(k0 + mrow) * DIM + dbase + q];
    float4 a0 = *(const float4*)(za + 0), a1 = *(const float4*)(za + 4);
    float4 a2 = *(const float4*)(za + 8), a3 = *(const float4*)(za + 12);
    float4 b0 = *(const float4*)(wa + 0), b1 = *(const float4*)(wa + 4);
    float4 b2 = *(const float4*)(wa + 8), b3 = *(const float4*)(wa + 12);
    float* Ap = &As[mrow * PADL + q];
    float* Wp = &Ws[mrow * PADL + q];
    Ap[0] = a0.x; Ap[1] = a0.y; Ap[2] = a0.z; Ap[3] = a0.w;
    Ap[4] = a1.x; Ap[5] = a1.y; Ap[6] = a1.z; Ap[7] = a1.w;
    Ap[8] = a2.x; Ap[9] = a2.y; Ap[10] = a2.z; Ap[11] = a2.w;
    Ap[12] = a3.x; Ap[13] = a3.y; Ap[14] = a3.z; Ap[15] = a3.w;
    Wp[0] = b0.x; Wp[1] = b0.y; Wp[2] = b0.z; Wp[3] = b0.w;
    Wp[4] = b1.x; Wp[5] = b1.y; Wp[6] = b1.z; Wp[7] = b1.w;
    Wp[8] = b2.x; Wp[9] = b2.y; Wp[10] = b2.z; Wp[11] = b2.w;
    Wp[12] = b3.x; Wp[13] = b3.y; Wp[14] = b3.z; Wp[15] = b3.w;
    __syncthreads();
#pragma unroll
    for (int d = 0; d < DK; ++d) {
      float a[8], b[8];
#pragma unroll
      for (int i = 0; i < 4; ++i) {
        a[i]     = As[(ty * 4 + i) * PADL + d];
        a[4 + i] = As[(64 + ty * 4 + i) * PADL + d];
        b[i]     = Ws[(tx * 4 + i) * PADL + d];
        b[4 + i] = Ws[(64 + tx * 4 + i) * PADL + d];
      }
#pragma unroll
      for (int i = 0; i < 8; ++i)
#pragma unroll
        for (int j = 0; j < 8; ++j) acc[i][j] = fmaf(a[i], b[j], acc[i][j]);
    }
  }

  float sc[8];
  int cols[8];
#pragma unroll
  for (int j = 0; j < 8; ++j) {
    int c = (j < 4) ? tx * 4 + j : 64 + tx * 4 + (j - 4);
    cols[j] = k0 + c;
    sc[j] = wsq[cols[j]];
  }
#pragma unroll
  for (int i = 0; i < 8; ++i) {
    int r = (i < 4) ? ty * 4 + i : 64 + ty * 4 + (i - 4);
    unsigned long long bv = ~0ull;
#pragma unroll
    for (int j = 0; j < 8; ++j) {
      float score = fmaf(-2.0f, acc[i][j], sc[j]);
      unsigned u = __float_as_uint(score);
      u ^= (unsigned)(((int)u >> 31) | 0x80000000);
      unsigned long long p = ((unsigned long long)u << 32) | (unsigned)cols[j];
      bv = p < bv ? p : bv;
    }
    atomicMin(&best[r], bv);
  }
  __syncthreads();
  if (tid < TM) atomicMin(&packed[m0 + tid], best[tid]);
}

// ---------------- K3: vectorized scatter (4 rows/block, float4) -----------------
__global__ __launch_bounds__(256) void k_scatter(float* __restrict__ zt,
                                                 const float* __restrict__ w,
                                                 const unsigned long long* __restrict__ packed,
                                                 float* __restrict__ emb_out,
                                                 float* __restrict__ loss_sum,
                                                 float* __restrict__ out3,
                                                 float* __restrict__ counts) {
  const int r = threadIdx.x >> 6, lane = threadIdx.x & 63;
  const int n = blockIdx.x * 4 + r;
  const int k = (int)(packed[n] & 0xFFFFFFFFull) & (KC - 1);
  if (lane == 0) {
    out3[n] = (float)k;
    atomicAdd(&counts[k], 1.0f);
  }
  const size_t zb = (size_t)n * DIM + lane * 4;
  const size_t wb = (size_t)k * DIM + lane * 4;
  float4 zv = *(const float4*)&zt[zb];
  float4 wv = *(const float4*)&w[wb];
  float4 df = { wv.x - zv.x, wv.y - zv.y, wv.z - zv.z, wv.w - zv.w };  // z_q - z
  float4 st = { zv.x + df.x, zv.y + df.y, zv.z + df.z, zv.w + df.w };  // straight-through
  *(float4*)&zt[zb] = st;
  atomicAdd(&emb_out[wb + 0], ONEMDECAY * zv.x);
  atomicAdd(&emb_out[wb + 1], ONEMDECAY * zv.y);
  atomicAdd(&emb_out[wb + 2], ONEMDECAY * zv.z);
  atomicAdd(&emb_out[wb + 3], ONEMDECAY * zv.w);
  float v = df.x * df.x + df.y * df.y + df.z * df.z + df.w * df.w;
#pragma unroll
  for (int off = 32; off; off >>= 1) v += __shfl_down(v, off);
  __shared__ float red[4];
  if (lane == 0) red[r] = v;
  __syncthreads();
  if (threadIdx.x == 0) atomicAdd(loss_sum, red[0] + red[1] + red[2] + red[3]);
}

// ---------------- K4 (fused): new_weight+out5 | scalars | transpose_out ---------
// blocks [0,4096): out4 float4 + out5 (ncs recomputed from counts; n_sum from
// scal[3]); block 4096: perplexity + loss scalars; [4097,4609): zt -> out0.
__global__ void k_final_fused(const float* __restrict__ emb_out, const float* __restrict__ cs,
                              const float* __restrict__ counts, const float* __restrict__ scal,
                              const float* __restrict__ zt, float* __restrict__ out4,
                              float* __restrict__ out5, float* __restrict__ out1,
                              float* __restrict__ out2, float* __restrict__ out0) {
  __shared__ float tile[64][65];
  if (blockIdx.x < (KC * DIM) / 1024) {
    int i4 = blockIdx.x * 256 + threadIdx.x;      // float4 index
    int k = i4 >> 6;                              // 64 float4 per row
    float c = counts[k];
    float ncs = cs[k] * DECAYF + ONEMDECAY * c;
    if ((i4 & 63) == 0) out5[k] = ncs;
    float nsum = DECAYF * scal[3] + ONEMDECAY * (float)NZ;  // sum(new_cluster_size)
    float smoothed = (ncs + EPSF) / (nsum + (float)KC * EPSF) * nsum;
    float inv = 1.0f / smoothed;
    float4 e = *(const float4*)&emb_out[(size_t)i4 * 4];
    float4 o = { e.x * inv, e.y * inv, e.z * inv, e.w * inv };
    *(float4*)&out4[(size_t)i4 * 4] = o;
  } else if (blockIdx.x == (KC * DIM) / 1024) {
    // perplexity over counts + loss scalar
    float t = 0.0f;
    for (int i = threadIdx.x; i < KC; i += 256) {
      float p = counts[i] * (1.0f / (float)NZ);
      t += p * logf(p + 1e-10f);
    }
#pragma unroll
    for (int off = 32; off; off >>= 1) t += __shfl_down(t, off);
    __shared__ float r2[4];
    if ((threadIdx.x & 63) == 0) r2[threadIdx.x >> 6] = t;
    __syncthreads();
    if (threadIdx.x == 0) {
      out2[0] = expf(-(r2[0] + r2[1] + r2[2] + r2[3]));
      out1[0] = BETAF * scal[0] / (float)(NZ * DIM);
    }
  } else {
    int flat = blockIdx.x - ((KC * DIM) / 1024 + 1);
    int hwb = (flat & 15) * 64, db = ((flat >> 4) & 3) * 64, b = flat >> 6;
    int lane = threadIdx.x & 63, sub = threadIdx.x >> 6;
#pragma unroll
    for (int i = 0; i < 16; ++i) {
      int hwof = sub * 16 + i;
      tile[hwof][lane] = zt[((size_t)(b * HW + hwb + hwof)) * DIM + db + lane];
    }
    __syncthreads();
#pragma unroll
    for (int i = 0; i < 16; ++i) {
      int dof = sub * 16 + i;
      out0[((size_t)(b * DIM + db + dof)) * HW + hwb + lane] = tile[lane][dof];
    }
  }
}

extern "C" void kernel_launch(void* const* d_in, const int* in_sizes, int n_in,
                              void* d_out, int out_size, void* d_ws, size_t ws_size,
                              hipStream_t stream) {
  const float* z  = (const float*)d_in[0];
  const float* w  = (const float*)d_in[1];
  const float* cs = (const float*)d_in[2];
  const float* ea = (const float*)d_in[3];
  float* out = (float*)d_out;
  float* ws  = (float*)d_ws;

  if (ws_size < (size_t)WS_FLOATS_OLD * sizeof(float)) return;  // fail loudly
  const bool use_mfma = ws_size >= (size_t)WS_FLOATS_NEW * sizeof(float);

  float* zt      = ws + W_ZT;
  float* wsq     = ws + W_WSQ;
  float* counts  = ws + W_CNT;
  float* scal    = ws + W_SCAL;
  unsigned long long* packed = (unsigned long long*)(ws + W_PACKED);
  _Float16* Acat = (_Float16*)(ws + W_ACAT);
  _Float16* Bcat = (_Float16*)(ws + W_BCAT);

  float* out0 = out + O_ZQ;
  float* out1 = out + O_LOSS;
  float* out2 = out + O_PERP;
  float* out3 = out + O_IDX;
  float* out4 = out + O_NW;
  float* out5 = out + O_NCS;
  float* out6 = out + O_NEA;

  hipMemsetAsync(counts, 0, (16384 + 4) * sizeof(float), stream);   // counts + scal
  hipMemsetAsync(packed, 0xFF, (size_t)NZ * sizeof(unsigned long long), stream);

  if (use_mfma) {
    k_prep_fused<true><<<KC / 4 + 512 + 64, 256, 0, stream>>>(z, w, ea, cs, zt, Acat,
                                                              wsq, Bcat, out6, scal);
    k_argmin_mfma<<<(KC / GBN) * (NZ / GBM), 512, 0, stream>>>(Acat, Bcat, wsq, packed);
  } else {
    k_prep_fused<false><<<KC / 4 + 512 + 64, 256, 0, stream>>>(z, w, ea, cs, zt, Acat,
                                                               wsq, Bcat, out6, scal);
    k_argmin_fp32<<<dim3(KC / TN, NZ / TM), 256, 0, stream>>>(zt, w, wsq, packed);
  }
  k_scatter<<<NZ / 4, 256, 0, stream>>>(zt, w, packed, out6, scal, out3, counts);
  k_final_fused<<<(KC * DIM) / 1024 + 1 + 512, 256, 0, stream>>>(out6, cs, counts, scal, zt,
                                                                 out4, out5, out1, out2, out0);
}

// Round 14
// 326.263 us; speedup vs baseline: 1.2366x; 1.0448x over previous
//
#include <hip/hip_runtime.h>

// Problem constants (from setup_inputs): z (8,256,32,32), weight (16384,256)
#define NB   8
#define DIM  256
#define HW   1024          // 32*32
#define NZ   8192          // NB*HW flattened z rows
#define KC   16384         // codebook entries
#define DECAYF 0.99f
#define ONEMDECAY 0.01f
#define EPSF 1e-5f
#define BETAF 0.25f
// logical K = 768 ([ah|al|ah].[bh|bh|bl]); physical layout is dedup'd:
// Acat = [ah|al] (512), Bcat = [bh|bl] (512); segment->phys remap in STAGE.
#define APHYS 512

typedef _Float16 half8 __attribute__((ext_vector_type(8)));
typedef _Float16 half4 __attribute__((ext_vector_type(4)));
typedef float floatx4 __attribute__((ext_vector_type(4)));

// Output offsets (floats) in d_out, in reference return order
#define O_ZQ   0u
#define O_LOSS 2097152u
#define O_PERP 2097153u
#define O_IDX  2097154u
#define O_NW   2105346u
#define O_NCS  6299650u
#define O_NEA  6316034u

// ws layout (floats)
#define W_ZT     0u          // 8192*256 fp32
#define W_WSQ    2097152u    // 16384
#define W_CNT    2113536u    // 16384            (zeroed by prep init blocks)
#define W_SCAL   2129920u    // 72: [0]=loss (zeroed), [8..71]=cs partials (pure write)
#define W_PACKED 2129992u    // 8192 u64 (byte off %8==0) (0xFF by prep init blocks)
#define W_ACAT   2146440u    // 8192*512 f16  (byte off %16==0)
#define W_BCAT   4243592u    // 16384*512 f16 (byte off %16==0)
#define WS_FLOATS_OLD 2146440u
#define WS_FLOATS_NEW 8437896u

// prep grid segmentation
#define NPREP  (KC / 4)     // 4096: w-prep
#define NTRANS 512          // z transpose
#define NSUM   64           // cs partial sums
#define NINIT  64           // counts/packed/scal init

// ---------------- K0 (fused): w-prep | z-transpose | cs-partials | buffer-init --
template <bool SPLIT>
__global__ void k_prep_fused(const float* __restrict__ z, const float* __restrict__ w,
                             const float* __restrict__ ea, const float* __restrict__ cs,
                             float* __restrict__ zt, _Float16* __restrict__ Acat,
                             float* __restrict__ wsq, _Float16* __restrict__ Bcat,
                             float* __restrict__ out6, float* __restrict__ scal,
                             float* __restrict__ counts,
                             unsigned long long* __restrict__ packed) {
  __shared__ float tile[64][65];
  if (blockIdx.x < NPREP) {
    int wave = threadIdx.x >> 6, lane = threadIdx.x & 63;
    int k = blockIdx.x * 4 + wave;
    float4 v = *(const float4*)&w[(size_t)k * DIM + lane * 4];
    float s = v.x * v.x + v.y * v.y + v.z * v.z + v.w * v.w;
#pragma unroll
    for (int off = 32; off; off >>= 1) s += __shfl_xor(s, off);
    if (lane == 0) wsq[k] = s;
    if (SPLIT) {
      half4 h = { (_Float16)v.x, (_Float16)v.y, (_Float16)v.z, (_Float16)v.w };
      half4 lo = { (_Float16)(v.x - (float)h.x), (_Float16)(v.y - (float)h.y),
                   (_Float16)(v.z - (float)h.z), (_Float16)(v.w - (float)h.w) };
      size_t bbase = (size_t)k * APHYS + lane * 4;
      *(half4*)&Bcat[bbase] = h;          // phys seg0 = bh
      *(half4*)&Bcat[bbase + 256] = lo;   // phys seg1 = bl
    }
    float4 e = *(const float4*)&ea[(size_t)k * DIM + lane * 4];
    float4 o = { DECAYF * e.x, DECAYF * e.y, DECAYF * e.z, DECAYF * e.w };
    *(float4*)&out6[(size_t)k * DIM + lane * 4] = o;
  } else if (blockIdx.x < NPREP + NTRANS) {
    int flat = blockIdx.x - NPREP;
    int hwb = (flat & 15) * 64, db = ((flat >> 4) & 3) * 64, b = flat >> 6;
    int lane = threadIdx.x & 63, sub = threadIdx.x >> 6;
#pragma unroll
    for (int i = 0; i < 16; ++i) {
      int dof = sub * 16 + i;
      tile[dof][lane] = z[((size_t)(b * DIM + db + dof)) * HW + hwb + lane];
    }
    __syncthreads();
#pragma unroll
    for (int i = 0; i < 16; ++i) {
      int hwof = sub * 16 + i;
      int n = b * HW + hwb + hwof;
      float val = tile[lane][hwof];
      zt[(size_t)n * DIM + db + lane] = val;
      if (SPLIT) {
        _Float16 h = (_Float16)val;
        _Float16 lo = (_Float16)(val - (float)h);
        size_t abase = (size_t)n * APHYS + db + lane;
        Acat[abase] = h;          // phys seg0 = ah
        Acat[abase + 256] = lo;   // phys seg1 = al
      }
    }
  } else if (blockIdx.x < NPREP + NTRANS + NSUM) {
    // cs partial sum -> scal[8+b] (pure write: no init dependency, no atomics)
    int b = blockIdx.x - (NPREP + NTRANS);
    float v = cs[b * 256 + threadIdx.x];
#pragma unroll
    for (int off = 32; off; off >>= 1) v += __shfl_xor(v, off);
    __shared__ float r[4];
    if ((threadIdx.x & 63) == 0) r[threadIdx.x >> 6] = v;
    __syncthreads();
    if (threadIdx.x == 0) scal[8 + b] = r[0] + r[1] + r[2] + r[3];
  } else {
    // buffer init: counts=0, packed=0xFF, scal[0..7]=0 (replaces 2 memsets;
    // stream-ordered before GEMM's atomicMin and scatter's atomicAdd)
    int idx = (blockIdx.x - (NPREP + NTRANS + NSUM)) * 256 + threadIdx.x;
    counts[idx] = 0.0f;
    if (idx < NZ) packed[idx] = ~0ull;
    if (idx < 8) scal[idx] = 0.0f;
  }
}

// ---------------- K2: 128x256 MFMA distance GEMM + fused argmin ------------------
// 8 waves (2M x 4N), per-wave output 64x64 (acc 64 regs -> 4 waves/SIMD ->
// 2 blocks/CU, 48 KB single-buffered LDS; cross-block overlap hides staging).
// Runtime K-loop (R10/R12/R13-verified): full unroll spills (R11, 119 MB
// scratch) under the launch_bounds(512,4) 128-reg/wave cap (acc 64 + arch 60).
#define GBM 128
#define GBN 256
#define GBK 64
#define NSTEP 12            // logical K = 768

__device__ __forceinline__ void gload16(const _Float16* g, _Float16* lds) {
  __builtin_amdgcn_global_load_lds((__attribute__((address_space(1))) void*)g,
                                   (__attribute__((address_space(3))) void*)lds, 16, 0, 0);
}

#define WAITVM0   asm volatile("s_waitcnt vmcnt(0)" ::: "memory")
#define WAITLGKM0 asm volatile("s_waitcnt lgkmcnt(0)" ::: "memory")
#define BAR       __builtin_amdgcn_s_barrier()

__global__ __launch_bounds__(512, 4) void k_argmin_mfma(const _Float16* __restrict__ Acat,
                                                        const _Float16* __restrict__ Bcat,
                                                        const float* __restrict__ wsq,
                                                        unsigned long long* __restrict__ packed) {
  __shared__ __align__(16) _Float16 As[GBM * GBK];   // 16 KB
  __shared__ __align__(16) _Float16 Bs[GBN * GBK];   // 32 KB  (total 48 KB)
  const int tid = threadIdx.x;
  const int w = tid >> 6, l = tid & 63;
  const int lr = l & 15, lc = l >> 4;
  const int wr = w >> 2, wc = w & 3;   // 2 x 4 wave grid, 64x64 per wave
  // XCD ownership: xcd = bid&7 owns 8 n-panels (L2-resident Bcat slice);
  // m-major order within the XCD reuses each A panel across its n-panels.
  const int bid = (int)blockIdx.x;
  const int xcd = bid & 7, local = bid >> 3;           // 4096 blocks total
  const int m0 = (local >> 3) * GBM;                   // 64 m-tiles
  const int n0 = (xcd * 8 + (local & 7)) * GBN;        // 64 n-tiles

  floatx4 acc[4][4];
#pragma unroll
  for (int i = 0; i < 4; ++i)
#pragma unroll
    for (int j = 0; j < 4; ++j) acc[i][j] = (floatx4){0.f, 0.f, 0.f, 0.f};

  // staging: LDS linear dest; global source pre-swizzled chunk^(row&7) so the
  // frag ds_read_b128 (row stride 128B) is bank-conflict-free.
  const int srow = (l >> 3);
  const int schk = (l & 7);

  // 6 gloads per thread per K-step: 2 A row-groups + 4 B row-groups of 8 rows.
  // logical step -> physical offsets: seg = STEP>>2 (0:ah.bh 1:al.bh 2:ah.bl)
#define STAGE(STEP)                                                               \
  {                                                                               \
    const int seg_ = (STEP) >> 2, ksub_ = (STEP) & 3;                             \
    const int aoff_ = (seg_ == 1 ? 256 : 0) + ksub_ * 64;                         \
    const int boff_ = (seg_ == 2 ? 256 : 0) + ksub_ * 64;                         \
    _Pragma("unroll")                                                             \
    for (int c = 0; c < 2; ++c) {                                                 \
      int row = (w * 2 + c) * 8 + srow;                                           \
      int sc_ = schk ^ (row & 7);                                                 \
      gload16(Acat + (size_t)(m0 + row) * APHYS + aoff_ + sc_ * 8,                \
              &As[(w * 2 + c) * 512]);                                            \
    }                                                                             \
    _Pragma("unroll")                                                             \
    for (int c = 0; c < 4; ++c) {                                                 \
      int row = (w * 4 + c) * 8 + srow;                                           \
      int sc_ = schk ^ (row & 7);                                                 \
      gload16(Bcat + (size_t)(n0 + row) * APHYS + boff_ + sc_ * 8,                \
              &Bs[(w * 4 + c) * 512]);                                            \
    }                                                                             \
  }

  for (int t = 0; t < NSTEP; ++t) {
    STAGE(t);
    WAITVM0;                 // my 6 stage-loads landed
    BAR;                     // everyone's landed -> tile valid
#pragma unroll
    for (int kk = 0; kk < 2; ++kk) {
      half8 af[4], bf[4];
#pragma unroll
      for (int mi = 0; mi < 4; ++mi) {
        int row = wr * 64 + mi * 16 + lr;
        int ch = (kk * 4 + lc) ^ (row & 7);
        af[mi] = *(const half8*)&As[row * GBK + ch * 8];
      }
#pragma unroll
      for (int ni = 0; ni < 4; ++ni) {
        int row = wc * 64 + ni * 16 + lr;
        int ch = (kk * 4 + lc) ^ (row & 7);
        bf[ni] = *(const half8*)&Bs[row * GBK + ch * 8];
      }
#pragma unroll
      for (int mi = 0; mi < 4; ++mi)
#pragma unroll
        for (int ni = 0; ni < 4; ++ni)
          acc[mi][ni] = __builtin_amdgcn_mfma_f32_16x16x32_f16(af[mi], bf[ni], acc[mi][ni], 0, 0, 0);
    }
    WAITLGKM0;               // my LDS reads retired
    BAR;                     // everyone done reading -> safe to overwrite
  }
#undef STAGE

  // epilogue: per-row argmin. C layout: col = lane&15, row = (lane>>4)*4 + reg.
  // best[] aliases the A buffer (final BAR above bounds all reads).
  unsigned long long* best = (unsigned long long*)&As[0];
  if (tid < GBM) best[tid] = ~0ull;
  __syncthreads();
  float sc4[4];
  int col4[4];
#pragma unroll
  for (int ni = 0; ni < 4; ++ni) {
    col4[ni] = n0 + wc * 64 + ni * 16 + lr;
    sc4[ni] = wsq[col4[ni]];
  }
#pragma unroll
  for (int mi = 0; mi < 4; ++mi) {
#pragma unroll
    for (int r = 0; r < 4; ++r) {
      unsigned long long bv = ~0ull;
#pragma unroll
      for (int ni = 0; ni < 4; ++ni) {
        float score = fmaf(-2.0f, acc[mi][ni][r], sc4[ni]);
        unsigned u = __float_as_uint(score);
        u ^= (unsigned)(((int)u >> 31) | 0x80000000);  // monotonic float->uint
        unsigned long long p = ((unsigned long long)u << 32) | (unsigned)col4[ni];
        bv = p < bv ? p : bv;
      }
#pragma unroll
      for (int off = 1; off < 16; off <<= 1) {
        unsigned long long o = __shfl_xor(bv, off);
        bv = o < bv ? o : bv;
      }
      if (lr == 0) atomicMin(&best[wr * 64 + mi * 16 + lc * 4 + r], bv);
    }
  }
  __syncthreads();
  if (tid < GBM) atomicMin(&packed[m0 + tid], best[tid]);
}

// ---------------- Fallback fp32 GEMM+argmin -------------------------------------
#define TM 128
#define TN 128
#define DK 32
#define PADL 33
__global__ __launch_bounds__(256) void k_argmin_fp32(const float* __restrict__ zt,
                                                     const float* __restrict__ w,
                                                     const float* __restrict__ wsq,
                                                     unsigned long long* __restrict__ packed) {
  __shared__ float As[TM * PADL];
  __shared__ float Ws[TN * PADL];
  __shared__ unsigned long long best[TM];
  const int tid = threadIdx.x;
  const int k0 = blockIdx.x * TN, m0 = blockIdx.y * TM;
  if (tid < TM) best[tid] = ~0ull;
  const int tx = tid & 15, ty = tid >> 4;
  const int mrow = tid & 127;
  const int q = (tid >> 7) * 16;

  float acc[8][8];
#pragma unroll
  for (int i = 0; i < 8; ++i)
#pragma unroll
    for (int j = 0; j < 8; ++j) acc[i][j] = 0.0f;

  for (int dbase = 0; dbase < DIM; dbase += DK) {
    __syncthreads();
    const float* za = &zt[(size_t)(m0 + mrow) * DIM + dbase + q];
    const float* wa = &w[(size_t)(k0 + mrow) * DIM + dbase + q];
    float4 a0 = *(const float4*)(za + 0), a1 = *(const float4*)(za + 4);
    float4 a2 = *(const float4*)(za + 8), a3 = *(const float4*)(za + 12);
    float4 b0 = *(const float4*)(wa + 0), b1 = *(const float4*)(wa + 4);
    float4 b2 = *(const float4*)(wa + 8), b3 = *(const float4*)(wa + 12);
    float* Ap = &As[mrow * PADL + q];
    float* Wp = &Ws[mrow * PADL + q];
    Ap[0] = a0.x; Ap[1] = a0.y; Ap[2] = a0.z; Ap[3] = a0.w;
    Ap[4] = a1.x; Ap[5] = a1.y; Ap[6] = a1.z; Ap[7] = a1.w;
    Ap[8] = a2.x; Ap[9] = a2.y; Ap[10] = a2.z; Ap[11] = a2.w;
    Ap[12] = a3.x; Ap[13] = a3.y; Ap[14] = a3.z; Ap[15] = a3.w;
    Wp[0] = b0.x; Wp[1] = b0.y; Wp[2] = b0.z; Wp[3] = b0.w;
    Wp[4] = b1.x; Wp[5] = b1.y; Wp[6] = b1.z; Wp[7] = b1.w;
    Wp[8] = b2.x; Wp[9] = b2.y; Wp[10] = b2.z; Wp[11] = b2.w;
    Wp[12] = b3.x; Wp[13] = b3.y; Wp[14] = b3.z; Wp[15] = b3.w;
    __syncthreads();
#pragma unroll
    for (int d = 0; d < DK; ++d) {
      float a[8], b[8];
#pragma unroll
      for (int i = 0; i < 4; ++i) {
        a[i]     = As[(ty * 4 + i) * PADL + d];
        a[4 + i] = As[(64 + ty * 4 + i) * PADL + d];
        b[i]     = Ws[(tx * 4 + i) * PADL + d];
        b[4 + i] = Ws[(64 + tx * 4 + i) * PADL + d];
      }
#pragma unroll
      for (int i = 0; i < 8; ++i)
#pragma unroll
        for (int j = 0; j < 8; ++j) acc[i][j] = fmaf(a[i], b[j], acc[i][j]);
    }
  }

  float sc[8];
  int cols[8];
#pragma unroll
  for (int j = 0; j < 8; ++j) {
    int c = (j < 4) ? tx * 4 + j : 64 + tx * 4 + (j - 4);
    cols[j] = k0 + c;
    sc[j] = wsq[cols[j]];
  }
#pragma unroll
  for (int i = 0; i < 8; ++i) {
    int r = (i < 4) ? ty * 4 + i : 64 + ty * 4 + (i - 4);
    unsigned long long bv = ~0ull;
#pragma unroll
    for (int j = 0; j < 8; ++j) {
      float score = fmaf(-2.0f, acc[i][j], sc[j]);
      unsigned u = __float_as_uint(score);
      u ^= (unsigned)(((int)u >> 31) | 0x80000000);
      unsigned long long p = ((unsigned long long)u << 32) | (unsigned)cols[j];
      bv = p < bv ? p : bv;
    }
    atomicMin(&best[r], bv);
  }
  __syncthreads();
  if (tid < TM) atomicMin(&packed[m0 + tid], best[tid]);
}

// ---------------- K3: vectorized scatter (4 rows/block, float4) -----------------
__global__ __launch_bounds__(256) void k_scatter(float* __restrict__ zt,
                                                 const float* __restrict__ w,
                                                 const unsigned long long* __restrict__ packed,
                                                 float* __restrict__ emb_out,
                                                 float* __restrict__ loss_sum,
                                                 float* __restrict__ out3,
                                                 float* __restrict__ counts) {
  const int r = threadIdx.x >> 6, lane = threadIdx.x & 63;
  const int n = blockIdx.x * 4 + r;
  const int k = (int)(packed[n] & 0xFFFFFFFFull) & (KC - 1);
  if (lane == 0) {
    out3[n] = (float)k;
    atomicAdd(&counts[k], 1.0f);
  }
  const size_t zb = (size_t)n * DIM + lane * 4;
  const size_t wb = (size_t)k * DIM + lane * 4;
  float4 zv = *(const float4*)&zt[zb];
  float4 wv = *(const float4*)&w[wb];
  float4 df = { wv.x - zv.x, wv.y - zv.y, wv.z - zv.z, wv.w - zv.w };  // z_q - z
  float4 st = { zv.x + df.x, zv.y + df.y, zv.z + df.z, zv.w + df.w };  // straight-through
  *(float4*)&zt[zb] = st;
  atomicAdd(&emb_out[wb + 0], ONEMDECAY * zv.x);
  atomicAdd(&emb_out[wb + 1], ONEMDECAY * zv.y);
  atomicAdd(&emb_out[wb + 2], ONEMDECAY * zv.z);
  atomicAdd(&emb_out[wb + 3], ONEMDECAY * zv.w);
  float v = df.x * df.x + df.y * df.y + df.z * df.z + df.w * df.w;
#pragma unroll
  for (int off = 32; off; off >>= 1) v += __shfl_down(v, off);
  __shared__ float red[4];
  if (lane == 0) red[r] = v;
  __syncthreads();
  if (threadIdx.x == 0) atomicAdd(loss_sum, red[0] + red[1] + red[2] + red[3]);
}

// ---------------- K4 (fused): new_weight+out5 | scalars | transpose_out ---------
// blocks [0,4096): out4 float4 + out5 (ncs from counts; nsum from 64 partials
// via in-wave butterfly); block 4096: perplexity + loss; [4097,4609): zt->out0.
__global__ void k_final_fused(const float* __restrict__ emb_out, const float* __restrict__ cs,
                              const float* __restrict__ counts, const float* __restrict__ scal,
                              const float* __restrict__ zt, float* __restrict__ out4,
                              float* __restrict__ out5, float* __restrict__ out1,
                              float* __restrict__ out2, float* __restrict__ out0) {
  __shared__ float tile[64][65];
  if (blockIdx.x < (KC * DIM) / 1024) {
    // nsum = 0.99*sum(cs) + 0.01*NZ; sum(cs) from 64 partials, 64-lane butterfly
    float pv = scal[8 + (threadIdx.x & 63)];
#pragma unroll
    for (int off = 32; off; off >>= 1) pv += __shfl_xor(pv, off);
    float nsum = DECAYF * pv + ONEMDECAY * (float)NZ;
    int i4 = blockIdx.x * 256 + threadIdx.x;      // float4 index
    int k = i4 >> 6;                              // 64 float4 per row
    float c = counts[k];
    float ncs = cs[k] * DECAYF + ONEMDECAY * c;
    if ((i4 & 63) == 0) out5[k] = ncs;
    float smoothed = (ncs + EPSF) / (nsum + (float)KC * EPSF) * nsum;
    float inv = 1.0f / smoothed;
    float4 e = *(const float4*)&emb_out[(size_t)i4 * 4];
    float4 o = { e.x * inv, e.y * inv, e.z * inv, e.w * inv };
    *(float4*)&out4[(size_t)i4 * 4] = o;
  } else if (blockIdx.x == (KC * DIM) / 1024) {
    // perplexity over counts + loss scalar
    float t = 0.0f;
    for (int i = threadIdx.x; i < KC; i += 256) {
      float p = counts[i] * (1.0f / (float)NZ);
      t += p * logf(p + 1e-10f);
    }
#pragma unroll
    for (int off = 32; off; off >>= 1) t += __shfl_down(t, off);
    __shared__ float r2[4];
    if ((threadIdx.x & 63) == 0) r2[threadIdx.x >> 6] = t;
    __syncthreads();
    if (threadIdx.x == 0) {
      out2[0] = expf(-(r2[0] + r2[1] + r2[2] + r2[3]));
      out1[0] = BETAF * scal[0] / (float)(NZ * DIM);
    }
  } else {
    int flat = blockIdx.x - ((KC * DIM) / 1024 + 1);
    int hwb = (flat & 15) * 64, db = ((flat >> 4) & 3) * 64, b = flat >> 6;
    int lane = threadIdx.x & 63, sub = threadIdx.x >> 6;
#pragma unroll
    for (int i = 0; i < 16; ++i) {
      int hwof = sub * 16 + i;
      tile[hwof][lane] = zt[((size_t)(b * HW + hwb + hwof)) * DIM + db + lane];
    }
    __syncthreads();
#pragma unroll
    for (int i = 0; i < 16; ++i) {
      int dof = sub * 16 + i;
      out0[((size_t)(b * DIM + db + dof)) * HW + hwb + lane] = tile[lane][dof];
    }
  }
}

extern "C" void kernel_launch(void* const* d_in, const int* in_sizes, int n_in,
                              void* d_out, int out_size, void* d_ws, size_t ws_size,
                              hipStream_t stream) {
  const float* z  = (const float*)d_in[0];
  const float* w  = (const float*)d_in[1];
  const float* cs = (const float*)d_in[2];
  const float* ea = (const float*)d_in[3];
  float* out = (float*)d_out;
  float* ws  = (float*)d_ws;

  if (ws_size < (size_t)WS_FLOATS_OLD * sizeof(float)) return;  // fail loudly
  const bool use_mfma = ws_size >= (size_t)WS_FLOATS_NEW * sizeof(float);

  float* zt      = ws + W_ZT;
  float* wsq     = ws + W_WSQ;
  float* counts  = ws + W_CNT;
  float* scal    = ws + W_SCAL;
  unsigned long long* packed = (unsigned long long*)(ws + W_PACKED);
  _Float16* Acat = (_Float16*)(ws + W_ACAT);
  _Float16* Bcat = (_Float16*)(ws + W_BCAT);

  float* out0 = out + O_ZQ;
  float* out1 = out + O_LOSS;
  float* out2 = out + O_PERP;
  float* out3 = out + O_IDX;
  float* out4 = out + O_NW;
  float* out5 = out + O_NCS;
  float* out6 = out + O_NEA;

  const int nprep = NPREP + NTRANS + NSUM + NINIT;
  if (use_mfma) {
    k_prep_fused<true><<<nprep, 256, 0, stream>>>(z, w, ea, cs, zt, Acat, wsq, Bcat,
                                                  out6, scal, counts, packed);
    k_argmin_mfma<<<(KC / GBN) * (NZ / GBM), 512, 0, stream>>>(Acat, Bcat, wsq, packed);
  } else {
    k_prep_fused<false><<<nprep, 256, 0, stream>>>(z, w, ea, cs, zt, Acat, wsq, Bcat,
                                                   out6, scal, counts, packed);
    k_argmin_fp32<<<dim3(KC / TN, NZ / TM), 256, 0, stream>>>(zt, w, wsq, packed);
  }
  k_scatter<<<NZ / 4, 256, 0, stream>>>(zt, w, packed, out6, scal, out3, counts);
  k_final_fused<<<(KC * DIM) / 1024 + 1 + 512, 256, 0, stream>>>(out6, cs, counts, scal, zt,
                                                                 out4, out5, out1, out2, out0);
}